// Round 13
// baseline (164.293 us; speedup 1.0000x reference)
//
#include <hip/hip_runtime.h>
#include <cstdint>
#include <cstddef>

#define TSEQ 512
#define DRNN 64
#define DIN  16

typedef float    f32x4 __attribute__((ext_vector_type(4)));
typedef unsigned u32x4 __attribute__((ext_vector_type(4)));
typedef _Float16 f16x8 __attribute__((ext_vector_type(8)));

#define MFMA16(A, B, C) __builtin_amdgcn_mfma_f32_16x16x32_f16((A), (B), (C), 0, 0, 0)
#define PIN(x) asm volatile("" : "+v"(x))

// pack two f32 -> f16x2 dword (v_cvt_pkrtz_f16_f32)
__device__ __forceinline__ unsigned packh(float a, float b) {
    return __builtin_bit_cast(unsigned, __builtin_amdgcn_cvt_pkrtz(a, b));
}
__device__ __forceinline__ f16x8 mkf(unsigned w0, unsigned w1, unsigned w2, unsigned w3) {
    u32x4 u = {w0, w1, w2, w3};
    return __builtin_bit_cast(f16x8, u);
}
__device__ __forceinline__ float tanh_fast(float x) {
    float e = __builtin_amdgcn_exp2f(x * 2.885390082f);
    float r = __builtin_amdgcn_rcpf(1.0f + e);
    return __builtin_fmaf(-2.0f, r, 1.0f);
}
// tanh of pre-scaled argument d = 2*log2(e)*z (scale folded into weights/bias)
__device__ __forceinline__ float tanh_pre(float d) {
    float e = __builtin_amdgcn_exp2f(d);
    float r = __builtin_amdgcn_rcpf(1.0f + e);
    return __builtin_fmaf(-2.0f, r, 1.0f);
}

// One fully-redundant step at time T, ring slot XI = T&3 (compile-time).
// State [h(64); x_T(16)], K-chunks c0,c1 = Wh, c2 = Wx (zero-padded to 32).
// Chain order: x-MFMA first (B ready early), then the two h-MFMAs (C-chained).
// Bh0/Bh1 produced here ARE next step's B operands (self-feeding layout, R12-verified).
#define STEPB(XI, FS, T, CLAMP) do {                                          \
    f32x4 xv_ = xreg[XI];                                                     \
    f16x8 Bx_ = mkf(packh(xv_[0], xv_[1]), packh(xv_[2], xv_[3]), 0u, 0u);    \
    { int tl_ = (T) + 4;                                                      \
      if (CLAMP) { if (tl_ > TSEQ - 1) tl_ = TSEQ - 1; }                      \
      xreg[XI] = *(const f32x4*)(xrow + (size_t)tl_ * DIN); }                 \
    f32x4 d0_ = MFMA16(W10, Bh1, MFMA16(W00, Bh0, MFMA16(W20, Bx_, bfr0)));   \
    f32x4 d1_ = MFMA16(W11, Bh1, MFMA16(W01, Bh0, MFMA16(W21, Bx_, bfr1)));   \
    f32x4 d2_ = MFMA16(W12, Bh1, MFMA16(W02, Bh0, MFMA16(W22, Bx_, bfr2)));   \
    f32x4 d3_ = MFMA16(W13, Bh1, MFMA16(W03, Bh0, MFMA16(W23, Bx_, bfr3)));   \
    float v00_ = tanh_pre(d0_[0]), v01_ = tanh_pre(d0_[1]);                   \
    float v02_ = tanh_pre(d0_[2]), v03_ = tanh_pre(d0_[3]);                   \
    float v10_ = tanh_pre(d1_[0]), v11_ = tanh_pre(d1_[1]);                   \
    float v12_ = tanh_pre(d1_[2]), v13_ = tanh_pre(d1_[3]);                   \
    Bh0 = mkf(packh(v00_, v01_), packh(v02_, v03_),                           \
              packh(v10_, v11_), packh(v12_, v13_));                          \
    float v20_ = tanh_pre(d2_[0]), v21_ = tanh_pre(d2_[1]);                   \
    float v22_ = tanh_pre(d2_[2]), v23_ = tanh_pre(d2_[3]);                   \
    float v30_ = tanh_pre(d3_[0]), v31_ = tanh_pre(d3_[1]);                   \
    float v32_ = tanh_pre(d3_[2]), v33_ = tanh_pre(d3_[3]);                   \
    Bh1 = mkf(packh(v20_, v21_), packh(v22_, v23_),                           \
              packh(v30_, v31_), packh(v32_, v33_));                         \
    if ((FS) >= 0) {                                                          \
        float f00_ = tanh_fast(v00_), f01_ = tanh_fast(v01_);                 \
        float f02_ = tanh_fast(v02_), f03_ = tanh_fast(v03_);                 \
        float f10_ = tanh_fast(v10_), f11_ = tanh_fast(v11_);                 \
        float f12_ = tanh_fast(v12_), f13_ = tanh_fast(v13_);                 \
        float f20_ = tanh_fast(v20_), f21_ = tanh_fast(v21_);                 \
        float f22_ = tanh_fast(v22_), f23_ = tanh_fast(v23_);                 \
        float f30_ = tanh_fast(v30_), f31_ = tanh_fast(v31_);                 \
        float f32_ = tanh_fast(v32_), f33_ = tanh_fast(v33_);                 \
        featF[(FS) >= 0 ? 2 * (FS) : 0] =                                     \
            mkf(packh(f00_, f01_), packh(f02_, f03_),                         \
                packh(f10_, f11_), packh(f12_, f13_));                        \
        featF[(FS) >= 0 ? 2 * (FS) + 1 : 0] =                                 \
            mkf(packh(f20_, f21_), packh(f22_, f23_),                         \
                packh(f30_, f31_), packh(f32_, f33_));                        \
    }                                                                         \
} while (0)

__global__ __launch_bounds__(64, 1) void rnn_nc(
    const float* __restrict__ X,
    const float* __restrict__ Wx,
    const float* __restrict__ Wh,
    const float* __restrict__ bias,
    const float* __restrict__ W1,
    const float* __restrict__ b1,
    const float* __restrict__ W2,
    const float* __restrict__ b2,
    float* __restrict__ out)
{
    const int lane = threadIdx.x & 63;
    const int li   = lane & 15;      // batch row (B/D col); weight M row for A
    const int g    = lane >> 4;      // k-slot group
    const int b0   = blockIdx.x * 16;
    const float S  = 2.885390082f;   // 2*log2(e), folded into Wh/Wx/bias

    // ---- persistent A fragments: [Wh | Wx]^T, 4 M-tiles x 3 K-chunks, f16 ----
    // slot map: k(c,g,e) = c*32 + (e<4 ? 4g+e : 16+4g+(e-4))
    auto loadWh = [&](int c, int mt) -> f16x8 {
        float wv[8];
        #pragma unroll
        for (int e = 0; e < 8; ++e) {
            int k = c * 32 + (e < 4 ? 4 * g + e : 16 + 4 * g + (e - 4));
            wv[e] = S * Wh[k * DRNN + 16 * mt + li];
        }
        return mkf(packh(wv[0], wv[1]), packh(wv[2], wv[3]),
                   packh(wv[4], wv[5]), packh(wv[6], wv[7]));
    };
    auto loadWx = [&](int mt) -> f16x8 {   // c2 chunk: x rows in e<4 slots
        float wv[4];
        #pragma unroll
        for (int e = 0; e < 4; ++e)
            wv[e] = S * Wx[(4 * g + e) * DRNN + 16 * mt + li];
        return mkf(packh(wv[0], wv[1]), packh(wv[2], wv[3]), 0u, 0u);
    };
    f16x8 W00 = loadWh(0, 0), W01 = loadWh(0, 1), W02 = loadWh(0, 2), W03 = loadWh(0, 3);
    f16x8 W10 = loadWh(1, 0), W11 = loadWh(1, 1), W12 = loadWh(1, 2), W13 = loadWh(1, 3);
    f16x8 W20 = loadWx(0),    W21 = loadWx(1),    W22 = loadWx(2),    W23 = loadWx(3);

    // scaled bias fragments (D rows 16mt+4g+q)
    f32x4 bfr0 = *(const f32x4*)(bias + 0 + 4 * g) * S;
    f32x4 bfr1 = *(const f32x4*)(bias + 16 + 4 * g) * S;
    f32x4 bfr2 = *(const f32x4*)(bias + 32 + 4 * g) * S;
    f32x4 bfr3 = *(const f32x4*)(bias + 48 + 4 * g) * S;

    // pin everything loop-invariant: volatile asm results can't be rematerialized,
    // so the compiler cannot sink these loads into the 512-step loop (R12's failure)
    PIN(W00); PIN(W01); PIN(W02); PIN(W03);
    PIN(W10); PIN(W11); PIN(W12); PIN(W13);
    PIN(W20); PIN(W21); PIN(W22); PIN(W23);
    PIN(bfr0); PIN(bfr1); PIN(bfr2); PIN(bfr3);

    // x ring, 4-deep: lane (li,g) owns X[b0+li][t][4g..4g+3]; slot i holds x_{t} for t%4==i
    const float* xrow = X + (size_t)(b0 + li) * TSEQ * DIN + 4 * g;
    f32x4 xreg[4];
    #pragma unroll
    for (int i = 0; i < 4; ++i)
        xreg[i] = *(const f32x4*)(xrow + (size_t)i * DIN);

    // h_{-1} = 0; feat fragments
    f16x8 Bh0 = mkf(0u, 0u, 0u, 0u), Bh1 = mkf(0u, 0u, 0u, 0u);
    f16x8 featF[6];
    #pragma unroll
    for (int i = 0; i < 6; ++i) featF[i] = mkf(0u, 0u, 0u, 0u);

    // main loop: steps 0..503 (126 x 4), clamp-free (T+4 <= 507)
    for (int tb = 0; tb < TSEQ - 8; tb += 4) {
        STEPB(0, -1, tb + 0, 0);
        STEPB(1, -1, tb + 1, 0);
        STEPB(2, -1, tb + 2, 0);
        STEPB(3, -1, tb + 3, 0);
    }
    // peeled: steps 504..511, clamped reloads, feat at 509/510/511
    STEPB(0, -1, 504, 1);
    STEPB(1, -1, 505, 1);
    STEPB(2, -1, 506, 1);
    STEPB(3, -1, 507, 1);
    STEPB(0, -1, 508, 1);
    STEPB(1,  0, 509, 1);
    STEPB(2,  1, 510, 1);
    STEPB(3,  2, 511, 1);

    // ---- MLP epilogue, all-register MFMA (verbatim from R12, verified) ----
    float p = 0.f;
    #pragma unroll
    for (int nt = 0; nt < 8; ++nt) {
        f32x4 a = *(const f32x4*)(b1 + nt * 16 + 4 * g);
        #pragma unroll
        for (int c6 = 0; c6 < 6; ++c6) {
            float wv[8];
            #pragma unroll
            for (int e = 0; e < 8; ++e) {
                int k = c6 * 32 + (e < 4 ? 4 * g + e : 16 + 4 * g + (e - 4));
                wv[e] = W1[k * 128 + nt * 16 + li];
            }
            f16x8 wf = mkf(packh(wv[0], wv[1]), packh(wv[2], wv[3]),
                           packh(wv[4], wv[5]), packh(wv[6], wv[7]));
            a = MFMA16(wf, featF[c6], a);
        }
        f32x4 w2v = *(const f32x4*)(W2 + nt * 16 + 4 * g);
        p += tanh_fast(a[0]) * w2v[0] + tanh_fast(a[1]) * w2v[1]
           + tanh_fast(a[2]) * w2v[2] + tanh_fast(a[3]) * w2v[3];
    }
    p += __shfl_xor(p, 16);
    p += __shfl_xor(p, 32);
    if (lane < 16) out[b0 + lane] = p + b2[0];
}

extern "C" void kernel_launch(void* const* d_in, const int* in_sizes, int n_in,
                              void* d_out, int out_size, void* d_ws, size_t ws_size,
                              hipStream_t stream) {
    const float* X    = (const float*)d_in[0];
    const float* Wx   = (const float*)d_in[1];
    const float* Wh   = (const float*)d_in[2];
    const float* bias = (const float*)d_in[3];
    const float* W1   = (const float*)d_in[4];
    const float* b1   = (const float*)d_in[5];
    const float* W2   = (const float*)d_in[6];
    const float* b2   = (const float*)d_in[7];
    rnn_nc<<<256, 64, 0, stream>>>(X, Wx, Wh, bias, W1, b1, W2, b2, (float*)d_out);
}

// Round 14
// 112.237 us; speedup vs baseline: 1.4638x; 1.4638x over previous
//
#include <hip/hip_runtime.h>
#include <cstdint>
#include <cstddef>

#define TSEQ 512
#define DRNN 64
#define DIN  16
#define FSTRIDE 66

typedef float    f32x4 __attribute__((ext_vector_type(4)));
typedef unsigned u32x4 __attribute__((ext_vector_type(4)));
typedef _Float16 f16x8 __attribute__((ext_vector_type(8)));

#define MFMA16(A, B, C) __builtin_amdgcn_mfma_f32_16x16x32_f16((A), (B), (C), 0, 0, 0)

// pack two f32 -> f16x2 dword (RTZ, single instr v_cvt_pkrtz_f16_f32)
__device__ __forceinline__ unsigned packh(float a, float b) {
    return __builtin_bit_cast(unsigned, __builtin_amdgcn_cvt_pkrtz(a, b));
}
__device__ __forceinline__ float tanh_fast(float x) {
    float e = __builtin_amdgcn_exp2f(x * 2.885390082f);
    float r = __builtin_amdgcn_rcpf(1.0f + e);
    return __builtin_fmaf(-2.0f, r, 1.0f);
}
// tanh of already-scaled argument d = 2*log2(e)*arg (scale folded into weights)
__device__ __forceinline__ float tanh_pre(float d) {
    float e = __builtin_amdgcn_exp2f(d);
    float r = __builtin_amdgcn_rcpf(1.0f + e);
    return __builtin_fmaf(-2.0f, r, 1.0f);
}

// Exchange layout: pair-word of h pair p=16c+8s+2g+r at dword
// ((c*4+g)*16+li)*4 + s*2+r. Consumer (g,li): c0 = b128 @ rd0, c1 = b128 @ rd1.
// Producer wave w: uint2 at wr.
//
// One step, slot I (compile-time). PR/PW: read/write exchange halves.
// REFILL: refill xacc[I] for t+16, load x for t+32.
// FS: compile-time feat slot (-1 = none).
// Fences are load-bearing (R10 A/B): they pin the ds_write early and keep the
// step body tight; removing them regressed 112->126 us.
#define STEPF(I, PR, PW, FS, REFILL, TB) do {                                 \
    u32x4 r0_ = *(const u32x4*)&PR[rd0];                                      \
    u32x4 r1_ = *(const u32x4*)&PR[rd1];                                      \
    f32x4 xc_ = xacc[I];                                                      \
    if (REFILL) {                                                             \
        f32x4 xv_ = xreg[I];                                                  \
        u32x4 bx_ = { packh(xv_[0], xv_[1]), packh(xv_[2], xv_[3]), 0u, 0u }; \
        xacc[I] = MFMA16(WxF, __builtin_bit_cast(f16x8, bx_), bfrS);          \
        int tl_ = (TB) + 32 + (I); if (tl_ > TSEQ - 1) tl_ = TSEQ - 1;        \
        xreg[I] = *(const f32x4*)(xrow + (size_t)tl_ * DIN);                  \
    }                                                                         \
    f16x8 Bh0_ = __builtin_bit_cast(f16x8, r0_);                              \
    f16x8 Bh1_ = __builtin_bit_cast(f16x8, r1_);                              \
    f32x4 P_ = MFMA16(WhF0, Bh0_, xc_);                                       \
    f32x4 Q_ = MFMA16(WhF1, Bh1_, zero4);                                     \
    f32x4 d_ = P_ + Q_;                                                       \
    float v0_ = tanh_pre(d_[0]), v1_ = tanh_pre(d_[1]);                       \
    float v2_ = tanh_pre(d_[2]), v3_ = tanh_pre(d_[3]);                       \
    { uint2 wv_; wv_.x = packh(v0_, v1_); wv_.y = packh(v2_, v3_);            \
      *(uint2*)&PW[wr] = wv_; }                                               \
    if ((FS) >= 0) {                                                          \
        float* fp_ = &feat[((FS) * 16 + li) * FSTRIDE + 16 * w + 4 * g];      \
        fp_[0] = tanh_fast(v0_); fp_[1] = tanh_fast(v1_);                     \
        fp_[2] = tanh_fast(v2_); fp_[3] = tanh_fast(v3_);                     \
    }                                                                         \
    asm volatile("s_waitcnt lgkmcnt(0)" ::: "memory");                        \
    __builtin_amdgcn_sched_barrier(0);                                        \
    __builtin_amdgcn_s_barrier();                                             \
    __builtin_amdgcn_sched_barrier(0);                                        \
} while (0)

__global__ __launch_bounds__(256, 1) void rnn_w4(
    const float* __restrict__ X,
    const float* __restrict__ Wx,
    const float* __restrict__ Wh,
    const float* __restrict__ bias,
    const float* __restrict__ W1,
    const float* __restrict__ b1,
    const float* __restrict__ W2,
    const float* __restrict__ b2,
    float* __restrict__ out)
{
    __shared__ unsigned hxn[2][512];          // pair-exchange, b128-friendly
    __shared__ float feat[3 * 16 * FSTRIDE];
    __shared__ float wpart[4][16];

    const int tid  = threadIdx.x;
    const int w    = tid >> 6;       // wave id = hidden tile mt
    const int lane = tid & 63;
    const int li   = lane & 15;      // batch row within tile
    const int g    = lane >> 4;      // k-slot group
    const int b0   = blockIdx.x * 16;
    const f32x4 zero4 = {0.f, 0.f, 0.f, 0.f};
    const float S = 2.885390082f;    // 2*log2(e), folded into Wh/Wx/bias

    // precomputed exchange dword indices (hoisted out of all 512 step bodies)
    const int rd0 = (g * 16 + li) * 4;
    const int rd1 = ((4 + g) * 16 + li) * 4;
    const int wr  = (((w >> 1) * 4 + g) * 16 + li) * 4 + (w & 1) * 2;

    // ---- persistent f16 A fragments for THIS wave's tile (mt = w) ----
    // slot map: k(c,g,e) = c*32 + (e<4 ? 4g+e : 16+4g+(e-4)); value S*Wh[k][16w+li]
    f16x8 WhF0, WhF1;
    {
        float wv[8];
        #pragma unroll
        for (int e = 0; e < 8; ++e) {
            int k = (e < 4 ? 4 * g + e : 16 + 4 * g + (e - 4));
            wv[e] = S * Wh[k * DRNN + 16 * w + li];
        }
        u32x4 u = { packh(wv[0],wv[1]), packh(wv[2],wv[3]),
                    packh(wv[4],wv[5]), packh(wv[6],wv[7]) };
        WhF0 = __builtin_bit_cast(f16x8, u);
        #pragma unroll
        for (int e = 0; e < 8; ++e) {
            int k = 32 + (e < 4 ? 4 * g + e : 16 + 4 * g + (e - 4));
            wv[e] = S * Wh[k * DRNN + 16 * w + li];
        }
        u32x4 v = { packh(wv[0],wv[1]), packh(wv[2],wv[3]),
                    packh(wv[4],wv[5]), packh(wv[6],wv[7]) };
        WhF1 = __builtin_bit_cast(f16x8, v);
    }
    f16x8 WxF;
    {
        float wv[4];
        #pragma unroll
        for (int e = 0; e < 4; ++e)
            wv[e] = S * Wx[(4 * g + e) * DRNN + 16 * w + li];
        u32x4 u = { packh(wv[0],wv[1]), packh(wv[2],wv[3]), 0u, 0u };
        WxF = __builtin_bit_cast(f16x8, u);
    }
    // scaled bias for D rows 16w + 4g + q
    f32x4 bfrS;
    {
        f32x4 b = *(const f32x4*)(bias + 16 * w + 4 * g);
        bfrS = b * S;
    }

    // x ring: lane (li,g) owns X[b0+li][t][4g..4g+3]
    const float* xrow = X + (size_t)(b0 + li) * TSEQ * DIN + 4 * g;
    f32x4 xreg[16], xacc[16];

    // zero exchange buffers (h_{-1} = 0)
    for (int idx = tid; idx < 2 * 512; idx += 256)
        (&hxn[0][0])[idx] = 0u;

    // prologue: xacc[i] = S*(bias + x_i @ Wx), i = 0..15; xreg[i] = x_{16+i}
    #pragma unroll
    for (int i = 0; i < 16; ++i)
        xreg[i] = *(const f32x4*)(xrow + (size_t)i * DIN);
    #pragma unroll
    for (int i = 0; i < 16; ++i) {
        f32x4 xv = xreg[i];
        u32x4 bx = { packh(xv[0], xv[1]), packh(xv[2], xv[3]), 0u, 0u };
        xacc[i] = MFMA16(WxF, __builtin_bit_cast(f16x8, bx), bfrS);
    }
    #pragma unroll
    for (int i = 0; i < 16; ++i)
        xreg[i] = *(const f32x4*)(xrow + (size_t)(16 + i) * DIN);
    __syncthreads();

    unsigned* hx0 = &hxn[0][0];
    unsigned* hx1 = &hxn[1][0];

    // main loop: steps 0..495 (31 blocks of 16); refill ring each step
    for (int tb = 0; tb < TSEQ - 16; tb += 16) {
        STEPF( 0, hx0, hx1, -1, 1, tb);
        STEPF( 1, hx1, hx0, -1, 1, tb);
        STEPF( 2, hx0, hx1, -1, 1, tb);
        STEPF( 3, hx1, hx0, -1, 1, tb);
        STEPF( 4, hx0, hx1, -1, 1, tb);
        STEPF( 5, hx1, hx0, -1, 1, tb);
        STEPF( 6, hx0, hx1, -1, 1, tb);
        STEPF( 7, hx1, hx0, -1, 1, tb);
        STEPF( 8, hx0, hx1, -1, 1, tb);
        STEPF( 9, hx1, hx0, -1, 1, tb);
        STEPF(10, hx0, hx1, -1, 1, tb);
        STEPF(11, hx1, hx0, -1, 1, tb);
        STEPF(12, hx0, hx1, -1, 1, tb);
        STEPF(13, hx1, hx0, -1, 1, tb);
        STEPF(14, hx0, hx1, -1, 1, tb);
        STEPF(15, hx1, hx0, -1, 1, tb);
    }
    // peeled final block: steps 496..511, no refill, feat at 509/510/511
    STEPF( 0, hx0, hx1, -1, 0, 0);
    STEPF( 1, hx1, hx0, -1, 0, 0);
    STEPF( 2, hx0, hx1, -1, 0, 0);
    STEPF( 3, hx1, hx0, -1, 0, 0);
    STEPF( 4, hx0, hx1, -1, 0, 0);
    STEPF( 5, hx1, hx0, -1, 0, 0);
    STEPF( 6, hx0, hx1, -1, 0, 0);
    STEPF( 7, hx1, hx0, -1, 0, 0);
    STEPF( 8, hx0, hx1, -1, 0, 0);
    STEPF( 9, hx1, hx0, -1, 0, 0);
    STEPF(10, hx0, hx1, -1, 0, 0);
    STEPF(11, hx1, hx0, -1, 0, 0);
    STEPF(12, hx0, hx1, -1, 0, 0);
    STEPF(13, hx1, hx0,  0, 0, 0);
    STEPF(14, hx0, hx1,  1, 0, 0);
    STEPF(15, hx1, hx0,  2, 0, 0);

    // ---- MLP epilogue (fp32 scalar, feat already tanh'd in LDS) ----
    __syncthreads();
    const int r  = tid & 15;   // batch row within block
    const int hc = tid >> 4;   // hidden-chunk 0..15 (8 hid units each)
    float acc8[8];
    #pragma unroll
    for (int u = 0; u < 8; ++u) acc8[u] = b1[hc * 8 + u];
    for (int s = 0; s < 3; ++s) {
        for (int kk = 0; kk < 64; ++kk) {
            float f = feat[(s * 16 + r) * FSTRIDE + kk];
            const float* wr2 = &W1[(s * 64 + kk) * 128 + hc * 8];
            f32x4 w0  = *(const f32x4*)wr2;
            f32x4 w1v = *(const f32x4*)(wr2 + 4);
            acc8[0] += f * w0[0];  acc8[1] += f * w0[1];
            acc8[2] += f * w0[2];  acc8[3] += f * w0[3];
            acc8[4] += f * w1v[0]; acc8[5] += f * w1v[1];
            acc8[6] += f * w1v[2]; acc8[7] += f * w1v[3];
        }
    }
    float p = 0.f;
    #pragma unroll
    for (int u = 0; u < 8; ++u) p += tanh_fast(acc8[u]) * W2[hc * 8 + u];
    p += __shfl_xor(p, 16);
    p += __shfl_xor(p, 32);
    if (g == 0) wpart[w][li] = p;
    __syncthreads();
    if (tid < 16)
        out[b0 + tid] = wpart[0][tid] + wpart[1][tid] + wpart[2][tid]
                      + wpart[3][tid] + b2[0];
}

extern "C" void kernel_launch(void* const* d_in, const int* in_sizes, int n_in,
                              void* d_out, int out_size, void* d_ws, size_t ws_size,
                              hipStream_t stream) {
    const float* X    = (const float*)d_in[0];
    const float* Wx   = (const float*)d_in[1];
    const float* Wh   = (const float*)d_in[2];
    const float* bias = (const float*)d_in[3];
    const float* W1   = (const float*)d_in[4];
    const float* b1   = (const float*)d_in[5];
    const float* W2   = (const float*)d_in[6];
    const float* b2   = (const float*)d_in[7];
    rnn_w4<<<256, 256, 0, stream>>>(X, Wx, Wh, bias, W1, b1, W2, b2, (float*)d_out);
}